// Round 1
// baseline (665.092 us; speedup 1.0000x reference)
//
#include <hip/hip_runtime.h>
#include <stdint.h>

#define NB 2
#define NC 256
#define NH 96
#define NW 160
#define HP 98     // NH + 2 (1-pad for 3x3 convs)
#define WP 162    // NW + 2
#define CATC 768  // concat channels
#define P8H 112   // NH + 16 (8-pad for correlation)
#define P8W 176   // NW + 16

typedef __bf16 bf16x8 __attribute__((ext_vector_type(8)));
typedef float f32x4 __attribute__((ext_vector_type(4)));

static __device__ __forceinline__ uint16_t f2bf(float f) {
  uint32_t u = __float_as_uint(f);
  return (uint16_t)((u + 0x7fffu + ((u >> 16) & 1u)) >> 16);  // RNE
}
static __device__ __forceinline__ float bflo(uint32_t u) { return __uint_as_float(u << 16); }
static __device__ __forceinline__ float bfhi(uint32_t u) { return __uint_as_float(u & 0xffff0000u); }

// ---------------- weight prep: W[co][ci][3][3] f32 -> [t][ci/32][co][32] bf16 ----------------
__global__ void __launch_bounds__(256) wprep_kernel(const float* __restrict__ wsrc,
                                                    uint16_t* __restrict__ dst, int cin) {
  int co = blockIdx.x;
  int nb = cin >> 5;
  for (int ci = threadIdx.x; ci < cin; ci += 256) {
    const float* s = wsrc + ((size_t)co * cin + ci) * 9;
    int cb = ci >> 5, cil = ci & 31;
#pragma unroll
    for (int t = 0; t < 9; ++t) {
      dst[(((size_t)t * nb + cb) * 256 + co) * 32 + cil] = f2bf(s[t]);
    }
  }
}

// ---------------- NCHW f32 -> padded NHWC bf16 (fcat sections + f1p8) ----------------
__global__ void __launch_bounds__(256) transpose_kernel(const float* __restrict__ f0,
                                                        const float* __restrict__ f1,
                                                        uint16_t* __restrict__ fcat,
                                                        uint16_t* __restrict__ f1p8) {
  __shared__ float tile[32][33];
  int tid = threadIdx.x;
  int tx = tid & 31, ty = tid >> 5;
  int xb = blockIdx.x;        // 0..4  (32 x each)
  int y = blockIdx.y;         // 0..95
  int z = blockIdx.z;         // b(2) * which(2) * cb(8)
  int b = z >> 4, which = (z >> 3) & 1, cb = z & 7;
  const float* src = which ? f1 : f0;
  int x0 = xb * 32;
#pragma unroll
  for (int j = 0; j < 4; ++j) {
    int c = cb * 32 + ty + j * 8;
    tile[ty + j * 8][tx] = src[((size_t)(b * NC + c) * NH + y) * NW + x0 + tx];
  }
  __syncthreads();
#pragma unroll
  for (int j = 0; j < 4; ++j) {
    int lx = ty + j * 8;
    int x = x0 + lx;
    int c = cb * 32 + tx;
    uint16_t v = f2bf(tile[tx][lx]);
    size_t base = ((size_t)(b * HP + y + 1) * WP + (x + 1)) * CATC;
    if (which == 0) {
      fcat[base + c] = v;
    } else {
      fcat[base + 512 + c] = v;
      f1p8[((size_t)(b * P8H + y + 8) * P8W + (x + 8)) * NC + c] = v;
    }
  }
}

// ---------------- correlation: writes fcat channels 256..511 ----------------
// block: 16 px (one row) x 256 threads (tx = px, pj = x-displacement); loop pi (y-displacement)
__global__ void __launch_bounds__(256) corr_kernel(const uint16_t* __restrict__ fcat,
                                                   const uint16_t* __restrict__ f1p8,
                                                   uint16_t* __restrict__ fout) {
  __shared__ __align__(16) uint16_t f0s[16 * 264];       // 16 px x 256 ch (row pad 264)
  __shared__ __align__(16) uint16_t f1s[16 * 32 * 40];   // 16 pi x 32 px x 32 ch (row pad 40)
  int tid = threadIdx.x;
  int tx = tid & 15, pj = tid >> 4;
  int x0 = blockIdx.x * 16;
  int y = blockIdx.y;
  int b = blockIdx.z;

  {  // stage f0 tile: 16 px x 256 ch
    int px = tid >> 4, part = tid & 15;
    size_t g = ((size_t)(b * HP + y + 1) * WP + (x0 + px + 1)) * CATC + part * 16;
    uint4 v0 = *(const uint4*)(fcat + g);
    uint4 v1 = *(const uint4*)(fcat + g + 8);
    *(uint4*)(f0s + px * 264 + part * 16) = v0;
    *(uint4*)(f0s + px * 264 + part * 16 + 8) = v1;
  }

  float acc[16];
#pragma unroll
  for (int i = 0; i < 16; ++i) acc[i] = 0.f;

  for (int cc = 0; cc < 8; ++cc) {  // 32-channel chunks
    __syncthreads();
    // stage f1: 16 rows (pi) x 32 px x 32 ch = 2048 x 16B units
#pragma unroll
    for (int k = 0; k < 8; ++k) {
      int u = k * 256 + tid;
      int q = u & 3, px = (u >> 2) & 31, pi = u >> 7;
      size_t g = ((size_t)(b * P8H + y + pi) * P8W + (x0 + px)) * NC + cc * 32 + q * 8;
      uint4 v = *(const uint4*)(f1p8 + g);
      *(uint4*)(f1s + (pi * 32 + px) * 40 + q * 8) = v;
    }
    float f0f[32];
    {
      const uint32_t* p = (const uint32_t*)(f0s + tx * 264 + cc * 32);
#pragma unroll
      for (int k = 0; k < 16; ++k) {
        uint32_t uu = p[k];
        f0f[2 * k] = bflo(uu);
        f0f[2 * k + 1] = bfhi(uu);
      }
    }
    __syncthreads();
#pragma unroll
    for (int pi = 0; pi < 16; ++pi) {
      const uint32_t* p = (const uint32_t*)(f1s + (pi * 32 + tx + pj) * 40);
      float a = acc[pi];
#pragma unroll
      for (int k = 0; k < 16; ++k) {
        uint32_t uu = p[k];
        a += f0f[2 * k] * bflo(uu);
        a += f0f[2 * k + 1] * bfhi(uu);
      }
      acc[pi] = a;
    }
  }
  size_t obase = ((size_t)(b * HP + y + 1) * WP + (x0 + tx + 1)) * CATC + 256 + pj;
#pragma unroll
  for (int pi = 0; pi < 16; ++pi) fout[obase + pi * 16] = f2bf(acc[pi]);
}

// ---------------- conv1: implicit GEMM, M=64 px, N=256 co, K=9*768 ----------------
__global__ void __launch_bounds__(256) conv1_kernel(const uint16_t* __restrict__ fcat,
                                                    const uint16_t* __restrict__ wp,
                                                    const float* __restrict__ bias,
                                                    uint16_t* __restrict__ hbuf) {
  __shared__ __align__(16) uint16_t As[64 * 40];   // 64 px x 32 ci (pad 40)
  __shared__ __align__(16) uint16_t Bs[256 * 40];  // 256 co x 32 ci (pad 40)
  int tid = threadIdx.x;
  int lane = tid & 63, w = tid >> 6;
  int x0 = blockIdx.x * 16, y0 = blockIdx.y * 4, b = blockIdx.z;

  int apx = tid >> 2, aq = tid & 3;
  int apy = apx >> 4, apxx = apx & 15;
  int lr = lane & 15, lk = lane >> 4;

  f32x4 acc[4][4];
#pragma unroll
  for (int m = 0; m < 4; ++m)
#pragma unroll
    for (int n = 0; n < 4; ++n) acc[m][n] = (f32x4){0.f, 0.f, 0.f, 0.f};

  for (int t = 0; t < 9; ++t) {
    int dy = t / 3, dx = t % 3;
    size_t arow = ((size_t)(b * HP + y0 + apy + dy) * WP + (x0 + apxx + dx)) * CATC;
    for (int cb = 0; cb < 24; ++cb) {
      __syncthreads();
      {  // A: 64 px x 64B
        uint4 v = *(const uint4*)(fcat + arow + cb * 32 + aq * 8);
        *(uint4*)(As + apx * 40 + aq * 8) = v;
      }
      {  // B: 16KB contiguous, coalesced
        const uint16_t* s = wp + ((size_t)(t * 24 + cb) * 256) * 32;
#pragma unroll
        for (int j = 0; j < 4; ++j) {
          int e = j * 2048 + tid * 8;
          uint4 v = *(const uint4*)(s + e);
          *(uint4*)(Bs + (e >> 5) * 40 + (e & 31)) = v;
        }
      }
      __syncthreads();
      bf16x8 af[4], bf[4];
#pragma unroll
      for (int m = 0; m < 4; ++m) af[m] = *(const bf16x8*)(As + (m * 16 + lr) * 40 + lk * 8);
#pragma unroll
      for (int n = 0; n < 4; ++n) bf[n] = *(const bf16x8*)(Bs + (w * 64 + n * 16 + lr) * 40 + lk * 8);
#pragma unroll
      for (int m = 0; m < 4; ++m)
#pragma unroll
        for (int n = 0; n < 4; ++n)
          acc[m][n] = __builtin_amdgcn_mfma_f32_16x16x32_bf16(af[m], bf[n], acc[m][n], 0, 0, 0);
    }
  }
  // epilogue: D col = co (lane&15), row = px ((lane>>4)*4+j); relu(acc + b1) -> padded NHWC bf16
#pragma unroll
  for (int n = 0; n < 4; ++n) {
    int co = w * 64 + n * 16 + lr;
    float bv = bias[co];
#pragma unroll
    for (int m = 0; m < 4; ++m) {
#pragma unroll
      for (int j = 0; j < 4; ++j) {
        int px = m * 16 + lk * 4 + j;
        int py = px >> 4, pxx = px & 15;
        float v = acc[m][n][j] + bv;
        v = v > 0.f ? v : 0.f;
        hbuf[((size_t)(b * HP + y0 + py + 1) * WP + (x0 + pxx + 1)) * NC + co] = f2bf(v);
      }
    }
  }
}

// ---------------- conv2: implicit GEMM, M=256 co, N=64 px, K=9*256; out = acc + b2 + f1 (NCHW f32) ----
__global__ void __launch_bounds__(256) conv2_kernel(const uint16_t* __restrict__ hbuf,
                                                    const uint16_t* __restrict__ wp,
                                                    const float* __restrict__ bias,
                                                    const float* __restrict__ f1,
                                                    float* __restrict__ out) {
  __shared__ __align__(16) uint16_t Xs[64 * 40];
  __shared__ __align__(16) uint16_t Ws[256 * 40];
  int tid = threadIdx.x;
  int lane = tid & 63, w = tid >> 6;
  int x0 = blockIdx.x * 16, y0 = blockIdx.y * 4, b = blockIdx.z;

  int apx = tid >> 2, aq = tid & 3;
  int apy = apx >> 4, apxx = apx & 15;
  int lr = lane & 15, lk = lane >> 4;

  f32x4 acc[4][4];
#pragma unroll
  for (int m = 0; m < 4; ++m)
#pragma unroll
    for (int n = 0; n < 4; ++n) acc[m][n] = (f32x4){0.f, 0.f, 0.f, 0.f};

  for (int t = 0; t < 9; ++t) {
    int dy = t / 3, dx = t % 3;
    size_t xrow = ((size_t)(b * HP + y0 + apy + dy) * WP + (x0 + apxx + dx)) * NC;
    for (int cb = 0; cb < 8; ++cb) {
      __syncthreads();
      {
        uint4 v = *(const uint4*)(hbuf + xrow + cb * 32 + aq * 8);
        *(uint4*)(Xs + apx * 40 + aq * 8) = v;
      }
      {
        const uint16_t* s = wp + ((size_t)(t * 8 + cb) * 256) * 32;
#pragma unroll
        for (int j = 0; j < 4; ++j) {
          int e = j * 2048 + tid * 8;
          uint4 v = *(const uint4*)(s + e);
          *(uint4*)(Ws + (e >> 5) * 40 + (e & 31)) = v;
        }
      }
      __syncthreads();
      bf16x8 aw[4], bx[4];
#pragma unroll
      for (int m = 0; m < 4; ++m) aw[m] = *(const bf16x8*)(Ws + (w * 64 + m * 16 + lr) * 40 + lk * 8);
#pragma unroll
      for (int n = 0; n < 4; ++n) bx[n] = *(const bf16x8*)(Xs + (n * 16 + lr) * 40 + lk * 8);
#pragma unroll
      for (int m = 0; m < 4; ++m)
#pragma unroll
        for (int n = 0; n < 4; ++n)
          acc[m][n] = __builtin_amdgcn_mfma_f32_16x16x32_bf16(aw[m], bx[n], acc[m][n], 0, 0, 0);
    }
  }
  // epilogue: D col = px (lane&15 = x within row, frag n = y-row), row = co
#pragma unroll
  for (int m = 0; m < 4; ++m) {
#pragma unroll
    for (int j = 0; j < 4; ++j) {
      int co = w * 64 + m * 16 + lk * 4 + j;
      float bv = bias[co];
#pragma unroll
      for (int n = 0; n < 4; ++n) {
        size_t idx = ((size_t)(b * NC + co) * NH + (y0 + n)) * NW + x0 + lr;
        out[idx] = acc[m][n][j] + bv + f1[idx];
      }
    }
  }
}

extern "C" void kernel_launch(void* const* d_in, const int* in_sizes, int n_in,
                              void* d_out, int out_size, void* d_ws, size_t ws_size,
                              hipStream_t stream) {
  (void)in_sizes; (void)n_in; (void)out_size; (void)ws_size;
  const float* f0 = (const float*)d_in[0];
  const float* f1 = (const float*)d_in[1];
  const float* W1 = (const float*)d_in[2];
  const float* b1 = (const float*)d_in[3];
  const float* W2 = (const float*)d_in[4];
  const float* b2 = (const float*)d_in[5];
  float* out = (float*)d_out;

  char* ws = (char*)d_ws;
  size_t s_fcat = (size_t)NB * HP * WP * CATC * 2;  // 48.8 MB
  size_t s_f1p8 = (size_t)NB * P8H * P8W * NC * 2;  // 20.2 MB
  size_t s_h = (size_t)NB * HP * WP * NC * 2;       // 16.3 MB
  size_t s_bp1 = (size_t)9 * 24 * 256 * 32 * 2;     // 3.5 MB
  uint16_t* fcat = (uint16_t*)ws;
  uint16_t* f1p8 = (uint16_t*)(ws + s_fcat);
  uint16_t* hbuf = (uint16_t*)(ws + s_fcat + s_f1p8);
  uint16_t* bp1 = (uint16_t*)(ws + s_fcat + s_f1p8 + s_h);
  uint16_t* bp2 = (uint16_t*)(ws + s_fcat + s_f1p8 + s_h + s_bp1);

  hipMemsetAsync(fcat, 0, s_fcat, stream);
  hipMemsetAsync(f1p8, 0, s_f1p8, stream);
  hipMemsetAsync(hbuf, 0, s_h, stream);

  wprep_kernel<<<256, 256, 0, stream>>>(W1, bp1, 768);
  wprep_kernel<<<256, 256, 0, stream>>>(W2, bp2, 256);
  transpose_kernel<<<dim3(5, 96, 32), 256, 0, stream>>>(f0, f1, fcat, f1p8);
  corr_kernel<<<dim3(10, 96, 2), 256, 0, stream>>>(fcat, f1p8, fcat);
  conv1_kernel<<<dim3(10, 24, 2), 256, 0, stream>>>(fcat, bp1, b1, hbuf);
  conv2_kernel<<<dim3(10, 24, 2), 256, 0, stream>>>(hbuf, bp2, b2, f1, out);
}

// Round 3
// 447.949 us; speedup vs baseline: 1.4848x; 1.4848x over previous
//
#include <hip/hip_runtime.h>
#include <stdint.h>

#define NB 2
#define NC 256
#define NH 96
#define NW 160
#define HP 98     // NH + 2 (1-pad for 3x3 convs)
#define WP 162    // NW + 2
#define CATC 768  // concat channels
#define P8H 112   // NH + 16 (8-pad for correlation)
#define P8W 176   // NW + 16

typedef __bf16 bf16x8 __attribute__((ext_vector_type(8)));
typedef float f32x4 __attribute__((ext_vector_type(4)));

static __device__ __forceinline__ uint16_t f2bf(float f) {
  uint32_t u = __float_as_uint(f);
  return (uint16_t)((u + 0x7fffu + ((u >> 16) & 1u)) >> 16);  // RNE
}

// ---------------- weight prep: W[co][ci][3][3] f32 -> [t][ci/32][co][32] bf16 ----------------
__global__ void __launch_bounds__(256) wprep_kernel(const float* __restrict__ wsrc,
                                                    uint16_t* __restrict__ dst, int cin) {
  int co = blockIdx.x;
  int nb = cin >> 5;
  for (int ci = threadIdx.x; ci < cin; ci += 256) {
    const float* s = wsrc + ((size_t)co * cin + ci) * 9;
    int cb = ci >> 5, cil = ci & 31;
#pragma unroll
    for (int t = 0; t < 9; ++t) {
      dst[(((size_t)t * nb + cb) * 256 + co) * 32 + cil] = f2bf(s[t]);
    }
  }
}

// ---------------- NCHW f32 -> padded NHWC bf16 (fcat sections + f1p8) ----------------
__global__ void __launch_bounds__(256) transpose_kernel(const float* __restrict__ f0,
                                                        const float* __restrict__ f1,
                                                        uint16_t* __restrict__ fcat,
                                                        uint16_t* __restrict__ f1p8) {
  __shared__ float tile[32][33];
  int tid = threadIdx.x;
  int tx = tid & 31, ty = tid >> 5;
  int xb = blockIdx.x;        // 0..4  (32 x each)
  int y = blockIdx.y;         // 0..95
  int z = blockIdx.z;         // b(2) * which(2) * cb(8)
  int b = z >> 4, which = (z >> 3) & 1, cb = z & 7;
  const float* src = which ? f1 : f0;
  int x0 = xb * 32;
#pragma unroll
  for (int j = 0; j < 4; ++j) {
    int c = cb * 32 + ty + j * 8;
    tile[ty + j * 8][tx] = src[((size_t)(b * NC + c) * NH + y) * NW + x0 + tx];
  }
  __syncthreads();
#pragma unroll
  for (int j = 0; j < 4; ++j) {
    int lx = ty + j * 8;
    int x = x0 + lx;
    int c = cb * 32 + tx;
    uint16_t v = f2bf(tile[tx][lx]);
    size_t base = ((size_t)(b * HP + y + 1) * WP + (x + 1)) * CATC;
    if (which == 0) {
      fcat[base + c] = v;
    } else {
      fcat[base + 512 + c] = v;
      f1p8[((size_t)(b * P8H + y + 8) * P8W + (x + 8)) * NC + c] = v;
    }
  }
}

// ---------------- correlation via MFMA band-GEMM: writes fcat channels 256..511 ----------------
// Per block: 16-px x-tile at row y. Cfull[xl, u] = sum_c f0[x0+xl,c] * f1p8[y+pi, x0+u, c],
// u = xl + pj in [0,32). 16x32x256 GEMM per pi; wave w handles pi = 4g + w. No LDS.
__global__ void __launch_bounds__(256) corr_kernel(const uint16_t* __restrict__ fcat,
                                                   const uint16_t* __restrict__ f1p8,
                                                   uint16_t* __restrict__ fout) {
  int tid = threadIdx.x;
  int lane = tid & 63, w = tid >> 6;
  int lr = lane & 15, lk = lane >> 4;
  int lin = blockIdx.x;                       // 0..959
  int wid = (lin & 7) * 120 + (lin >> 3);     // XCD swizzle: y-contiguous chunks per XCD
  int y = wid % 96, xt = wid / 96;
  int b = blockIdx.y;
  int x0 = xt * 16;

  // A-frags: f0 (fcat ch 0..255), px = x0+lr, k-chunk lk*8 within each 32-ch step
  bf16x8 af[8];
  const uint16_t* abase = fcat + ((size_t)(b * HP + y + 1) * WP + (x0 + lr + 1)) * CATC + lk * 8;
#pragma unroll
  for (int kk = 0; kk < 8; ++kk) af[kk] = *(const bf16x8*)(abase + kk * 32);

  for (int g = 0; g < 4; ++g) {
    int pi = g * 4 + w;
    const uint16_t* bbase =
        f1p8 + ((size_t)(b * P8H + y + pi) * P8W + x0) * NC + lk * 8;
    bf16x8 bf0[8], bf1[8];
#pragma unroll
    for (int kk = 0; kk < 8; ++kk) {
      bf0[kk] = *(const bf16x8*)(bbase + (size_t)lr * NC + kk * 32);
      bf1[kk] = *(const bf16x8*)(bbase + (size_t)(16 + lr) * NC + kk * 32);
    }
    f32x4 acc0 = (f32x4){0.f, 0.f, 0.f, 0.f};
    f32x4 acc1 = (f32x4){0.f, 0.f, 0.f, 0.f};
#pragma unroll
    for (int kk = 0; kk < 8; ++kk) {
      acc0 = __builtin_amdgcn_mfma_f32_16x16x32_bf16(af[kk], bf0[kk], acc0, 0, 0, 0);
      acc1 = __builtin_amdgcn_mfma_f32_16x16x32_bf16(af[kk], bf1[kk], acc1, 0, 0, 0);
    }
    // D layout: col (=u within tile) = lane&15, row (=xl) = (lane>>4)*4 + j
    size_t orow = ((size_t)(b * HP + y + 1) * WP + (x0 + 1)) * CATC + 256 + (size_t)pi * 16;
#pragma unroll
    for (int j = 0; j < 4; ++j) {
      int xl = lk * 4 + j;
      int pj0 = lr - xl;        // nt=0: u = lr
      if (pj0 >= 0) fout[orow + (size_t)xl * CATC + pj0] = f2bf(acc0[j]);
      int pj1 = 16 + lr - xl;   // nt=1: u = 16 + lr
      if (pj1 < 16) fout[orow + (size_t)xl * CATC + pj1] = f2bf(acc1[j]);
    }
  }
}

// ---------------- conv1: implicit GEMM, M=64 px, N=256 co, K=9*768 ----------------
__global__ void __launch_bounds__(256) conv1_kernel(const uint16_t* __restrict__ fcat,
                                                    const uint16_t* __restrict__ wp,
                                                    const float* __restrict__ bias,
                                                    uint16_t* __restrict__ hbuf) {
  __shared__ __align__(16) uint16_t As[64 * 40];   // 64 px x 32 ci (pad 40)
  __shared__ __align__(16) uint16_t Bs[256 * 40];  // 256 co x 32 ci (pad 40)
  int tid = threadIdx.x;
  int lane = tid & 63, w = tid >> 6;
  int x0 = blockIdx.x * 16, y0 = blockIdx.y * 4, b = blockIdx.z;

  int apx = tid >> 2, aq = tid & 3;
  int apy = apx >> 4, apxx = apx & 15;
  int lr = lane & 15, lk = lane >> 4;

  f32x4 acc[4][4];
#pragma unroll
  for (int m = 0; m < 4; ++m)
#pragma unroll
    for (int n = 0; n < 4; ++n) acc[m][n] = (f32x4){0.f, 0.f, 0.f, 0.f};

  for (int t = 0; t < 9; ++t) {
    int dy = t / 3, dx = t % 3;
    size_t arow = ((size_t)(b * HP + y0 + apy + dy) * WP + (x0 + apxx + dx)) * CATC;
    for (int cb = 0; cb < 24; ++cb) {
      __syncthreads();
      {  // A: 64 px x 64B
        uint4 v = *(const uint4*)(fcat + arow + cb * 32 + aq * 8);
        *(uint4*)(As + apx * 40 + aq * 8) = v;
      }
      {  // B: 16KB contiguous, coalesced
        const uint16_t* s = wp + ((size_t)(t * 24 + cb) * 256) * 32;
#pragma unroll
        for (int j = 0; j < 4; ++j) {
          int e = j * 2048 + tid * 8;
          uint4 v = *(const uint4*)(s + e);
          *(uint4*)(Bs + (e >> 5) * 40 + (e & 31)) = v;
        }
      }
      __syncthreads();
      bf16x8 af[4], bf[4];
#pragma unroll
      for (int m = 0; m < 4; ++m) af[m] = *(const bf16x8*)(As + (m * 16 + lr) * 40 + lk * 8);
#pragma unroll
      for (int n = 0; n < 4; ++n) bf[n] = *(const bf16x8*)(Bs + (w * 64 + n * 16 + lr) * 40 + lk * 8);
#pragma unroll
      for (int m = 0; m < 4; ++m)
#pragma unroll
        for (int n = 0; n < 4; ++n)
          acc[m][n] = __builtin_amdgcn_mfma_f32_16x16x32_bf16(af[m], bf[n], acc[m][n], 0, 0, 0);
    }
  }
  // epilogue: D col = co (lane&15), row = px ((lane>>4)*4+j); relu(acc + b1) -> padded NHWC bf16
#pragma unroll
  for (int n = 0; n < 4; ++n) {
    int co = w * 64 + n * 16 + lr;
    float bv = bias[co];
#pragma unroll
    for (int m = 0; m < 4; ++m) {
#pragma unroll
      for (int j = 0; j < 4; ++j) {
        int px = m * 16 + lk * 4 + j;
        int py = px >> 4, pxx = px & 15;
        float v = acc[m][n][j] + bv;
        v = v > 0.f ? v : 0.f;
        hbuf[((size_t)(b * HP + y0 + py + 1) * WP + (x0 + pxx + 1)) * NC + co] = f2bf(v);
      }
    }
  }
}

// ---------------- conv2: implicit GEMM, M=256 co, N=64 px, K=9*256; out = acc + b2 + f1 (NCHW f32) ----
__global__ void __launch_bounds__(256) conv2_kernel(const uint16_t* __restrict__ hbuf,
                                                    const uint16_t* __restrict__ wp,
                                                    const float* __restrict__ bias,
                                                    const float* __restrict__ f1,
                                                    float* __restrict__ out) {
  __shared__ __align__(16) uint16_t Xs[64 * 40];
  __shared__ __align__(16) uint16_t Ws[256 * 40];
  int tid = threadIdx.x;
  int lane = tid & 63, w = tid >> 6;
  int x0 = blockIdx.x * 16, y0 = blockIdx.y * 4, b = blockIdx.z;

  int apx = tid >> 2, aq = tid & 3;
  int apy = apx >> 4, apxx = apx & 15;
  int lr = lane & 15, lk = lane >> 4;

  f32x4 acc[4][4];
#pragma unroll
  for (int m = 0; m < 4; ++m)
#pragma unroll
    for (int n = 0; n < 4; ++n) acc[m][n] = (f32x4){0.f, 0.f, 0.f, 0.f};

  for (int t = 0; t < 9; ++t) {
    int dy = t / 3, dx = t % 3;
    size_t xrow = ((size_t)(b * HP + y0 + apy + dy) * WP + (x0 + apxx + dx)) * NC;
    for (int cb = 0; cb < 8; ++cb) {
      __syncthreads();
      {
        uint4 v = *(const uint4*)(hbuf + xrow + cb * 32 + aq * 8);
        *(uint4*)(Xs + apx * 40 + aq * 8) = v;
      }
      {
        const uint16_t* s = wp + ((size_t)(t * 8 + cb) * 256) * 32;
#pragma unroll
        for (int j = 0; j < 4; ++j) {
          int e = j * 2048 + tid * 8;
          uint4 v = *(const uint4*)(s + e);
          *(uint4*)(Ws + (e >> 5) * 40 + (e & 31)) = v;
        }
      }
      __syncthreads();
      bf16x8 aw[4], bx[4];
#pragma unroll
      for (int m = 0; m < 4; ++m) aw[m] = *(const bf16x8*)(Ws + (w * 64 + m * 16 + lr) * 40 + lk * 8);
#pragma unroll
      for (int n = 0; n < 4; ++n) bx[n] = *(const bf16x8*)(Xs + (n * 16 + lr) * 40 + lk * 8);
#pragma unroll
      for (int m = 0; m < 4; ++m)
#pragma unroll
        for (int n = 0; n < 4; ++n)
          acc[m][n] = __builtin_amdgcn_mfma_f32_16x16x32_bf16(aw[m], bx[n], acc[m][n], 0, 0, 0);
    }
  }
  // epilogue: D col = px (lane&15 = x within row, frag n = y-row), row = co
#pragma unroll
  for (int m = 0; m < 4; ++m) {
#pragma unroll
    for (int j = 0; j < 4; ++j) {
      int co = w * 64 + m * 16 + lk * 4 + j;
      float bv = bias[co];
#pragma unroll
      for (int n = 0; n < 4; ++n) {
        size_t idx = ((size_t)(b * NC + co) * NH + (y0 + n)) * NW + x0 + lr;
        out[idx] = acc[m][n][j] + bv + f1[idx];
      }
    }
  }
}

extern "C" void kernel_launch(void* const* d_in, const int* in_sizes, int n_in,
                              void* d_out, int out_size, void* d_ws, size_t ws_size,
                              hipStream_t stream) {
  (void)in_sizes; (void)n_in; (void)out_size; (void)ws_size;
  const float* f0 = (const float*)d_in[0];
  const float* f1 = (const float*)d_in[1];
  const float* W1 = (const float*)d_in[2];
  const float* b1 = (const float*)d_in[3];
  const float* W2 = (const float*)d_in[4];
  const float* b2 = (const float*)d_in[5];
  float* out = (float*)d_out;

  char* ws = (char*)d_ws;
  size_t s_fcat = (size_t)NB * HP * WP * CATC * 2;  // 48.8 MB
  size_t s_f1p8 = (size_t)NB * P8H * P8W * NC * 2;  // 20.2 MB
  size_t s_h = (size_t)NB * HP * WP * NC * 2;       // 16.3 MB
  size_t s_bp1 = (size_t)9 * 24 * 256 * 32 * 2;     // 3.5 MB
  uint16_t* fcat = (uint16_t*)ws;
  uint16_t* f1p8 = (uint16_t*)(ws + s_fcat);
  uint16_t* hbuf = (uint16_t*)(ws + s_fcat + s_f1p8);
  uint16_t* bp1 = (uint16_t*)(ws + s_fcat + s_f1p8 + s_h);
  uint16_t* bp2 = (uint16_t*)(ws + s_fcat + s_f1p8 + s_h + s_bp1);

  hipMemsetAsync(fcat, 0, s_fcat, stream);
  hipMemsetAsync(f1p8, 0, s_f1p8, stream);
  hipMemsetAsync(hbuf, 0, s_h, stream);

  wprep_kernel<<<256, 256, 0, stream>>>(W1, bp1, 768);
  wprep_kernel<<<256, 256, 0, stream>>>(W2, bp2, 256);
  transpose_kernel<<<dim3(5, 96, 32), 256, 0, stream>>>(f0, f1, fcat, f1p8);
  corr_kernel<<<dim3(960, 2), 256, 0, stream>>>(fcat, f1p8, fcat);
  conv1_kernel<<<dim3(10, 24, 2), 256, 0, stream>>>(fcat, bp1, b1, hbuf);
  conv2_kernel<<<dim3(10, 24, 2), 256, 0, stream>>>(hbuf, bp2, b2, f1, out);
}

// Round 4
// 432.660 us; speedup vs baseline: 1.5372x; 1.0353x over previous
//
#include <hip/hip_runtime.h>
#include <stdint.h>

#define NB 2
#define NC 256
#define NH 96
#define NW 160
#define HP 98     // NH + 2 (1-pad for 3x3 convs)
#define WP 162    // NW + 2
#define CATC 768  // concat channels
#define P8H 112   // NH + 16 (8-pad for correlation)
#define P8W 176   // NW + 16

typedef __bf16 bf16x8 __attribute__((ext_vector_type(8)));
typedef float f32x4 __attribute__((ext_vector_type(4)));

static __device__ __forceinline__ uint16_t f2bf(float f) {
  uint32_t u = __float_as_uint(f);
  return (uint16_t)((u + 0x7fffu + ((u >> 16) & 1u)) >> 16);  // RNE
}

static __device__ __forceinline__ void gload16(const void* g, void* l) {
  __builtin_amdgcn_global_load_lds(
      (const __attribute__((address_space(1))) uint32_t*)g,
      (__attribute__((address_space(3))) uint32_t*)l, 16, 0, 0);
}

// ---------------- weight prep: W[co][ci][3][3] f32 -> [t*(ci/32)+cb][co][32] bf16 ----------------
__global__ void __launch_bounds__(256) wprep_kernel(const float* __restrict__ wsrc,
                                                    uint16_t* __restrict__ dst, int cin) {
  int co = blockIdx.x;
  int nb = cin >> 5;
  for (int ci = threadIdx.x; ci < cin; ci += 256) {
    const float* s = wsrc + ((size_t)co * cin + ci) * 9;
    int cb = ci >> 5, cil = ci & 31;
#pragma unroll
    for (int t = 0; t < 9; ++t) {
      dst[(((size_t)t * nb + cb) * 256 + co) * 32 + cil] = f2bf(s[t]);
    }
  }
}

// ---------------- NCHW f32 -> padded NHWC bf16 (fcat sections + f1p8) ----------------
__global__ void __launch_bounds__(256) transpose_kernel(const float* __restrict__ f0,
                                                        const float* __restrict__ f1,
                                                        uint16_t* __restrict__ fcat,
                                                        uint16_t* __restrict__ f1p8) {
  __shared__ float tile[32][33];
  int tid = threadIdx.x;
  int tx = tid & 31, ty = tid >> 5;
  int xb = blockIdx.x;        // 0..4  (32 x each)
  int y = blockIdx.y;         // 0..95
  int z = blockIdx.z;         // b(2) * which(2) * cb(8)
  int b = z >> 4, which = (z >> 3) & 1, cb = z & 7;
  const float* src = which ? f1 : f0;
  int x0 = xb * 32;
#pragma unroll
  for (int j = 0; j < 4; ++j) {
    int c = cb * 32 + ty + j * 8;
    tile[ty + j * 8][tx] = src[((size_t)(b * NC + c) * NH + y) * NW + x0 + tx];
  }
  __syncthreads();
#pragma unroll
  for (int j = 0; j < 4; ++j) {
    int lx = ty + j * 8;
    int x = x0 + lx;
    int c = cb * 32 + tx;
    uint16_t v = f2bf(tile[tx][lx]);
    size_t base = ((size_t)(b * HP + y + 1) * WP + (x + 1)) * CATC;
    if (which == 0) {
      fcat[base + c] = v;
    } else {
      fcat[base + 512 + c] = v;
      f1p8[((size_t)(b * P8H + y + 8) * P8W + (x + 8)) * NC + c] = v;
    }
  }
}

// ---------------- correlation via MFMA band-GEMM: writes fcat channels 256..511 ----------------
__global__ void __launch_bounds__(256) corr_kernel(const uint16_t* __restrict__ fcat,
                                                   const uint16_t* __restrict__ f1p8,
                                                   uint16_t* __restrict__ fout) {
  int tid = threadIdx.x;
  int lane = tid & 63, w = tid >> 6;
  int lr = lane & 15, lk = lane >> 4;
  int lin = blockIdx.x;                       // 0..959
  int wid = (lin & 7) * 120 + (lin >> 3);     // XCD swizzle: y-contiguous chunks per XCD
  int y = wid % 96, xt = wid / 96;
  int b = blockIdx.y;
  int x0 = xt * 16;

  bf16x8 af[8];
  const uint16_t* abase = fcat + ((size_t)(b * HP + y + 1) * WP + (x0 + lr + 1)) * CATC + lk * 8;
#pragma unroll
  for (int kk = 0; kk < 8; ++kk) af[kk] = *(const bf16x8*)(abase + kk * 32);

  for (int g = 0; g < 4; ++g) {
    int pi = g * 4 + w;
    const uint16_t* bbase =
        f1p8 + ((size_t)(b * P8H + y + pi) * P8W + x0) * NC + lk * 8;
    bf16x8 bf0[8], bf1[8];
#pragma unroll
    for (int kk = 0; kk < 8; ++kk) {
      bf0[kk] = *(const bf16x8*)(bbase + (size_t)lr * NC + kk * 32);
      bf1[kk] = *(const bf16x8*)(bbase + (size_t)(16 + lr) * NC + kk * 32);
    }
    f32x4 acc0 = (f32x4){0.f, 0.f, 0.f, 0.f};
    f32x4 acc1 = (f32x4){0.f, 0.f, 0.f, 0.f};
#pragma unroll
    for (int kk = 0; kk < 8; ++kk) {
      acc0 = __builtin_amdgcn_mfma_f32_16x16x32_bf16(af[kk], bf0[kk], acc0, 0, 0, 0);
      acc1 = __builtin_amdgcn_mfma_f32_16x16x32_bf16(af[kk], bf1[kk], acc1, 0, 0, 0);
    }
    size_t orow = ((size_t)(b * HP + y + 1) * WP + (x0 + 1)) * CATC + 256 + (size_t)pi * 16;
#pragma unroll
    for (int j = 0; j < 4; ++j) {
      int xl = lk * 4 + j;
      int pj0 = lr - xl;
      if (pj0 >= 0) fout[orow + (size_t)xl * CATC + pj0] = f2bf(acc0[j]);
      int pj1 = 16 + lr - xl;
      if (pj1 < 16) fout[orow + (size_t)xl * CATC + pj1] = f2bf(acc1[j]);
    }
  }
}

// ---------------- conv1: pipelined implicit GEMM ----------------
// BM=128 px (16x x 8y), BN=256 co, BK=32, 8 waves. A (fcat) triple-buffered in LDS via
// global_load_lds; B (weights, L2-resident) global->reg with 1-step prefetch.
// Counted vmcnt (never 0) + raw s_barrier per step.
__global__ __launch_bounds__(512, 2) void conv1_kernel(const uint16_t* __restrict__ fcat,
                                                       const uint16_t* __restrict__ wp,
                                                       const float* __restrict__ bias,
                                                       uint16_t* __restrict__ hbuf) {
  constexpr int CBS = 24, NT = 9 * CBS;  // 216 K-steps
  __shared__ __align__(16) uint16_t As[3][128 * 32];  // 3 x 8 KB
  int tid = threadIdx.x;
  int w = tid >> 6, lane = tid & 63;
  int lr = lane & 15, lk = lane >> 4;
  int wr = w >> 2, wc = w & 3;  // px-half, co-quarter

  int orig = blockIdx.x;                     // 0..239
  int swz = (orig & 7) * 30 + (orig >> 3);   // XCD-bijective (240 % 8 == 0)
  int b = swz / 120, rem = swz % 120;
  int xt = rem / 12, yt = rem % 12;
  int x0 = xt * 16, y0 = yt * 8;

  // A staging: wave w stages px-rows w*16..w*16+15; lane l -> row w*16+(l>>2), chunk l&3
  int sr = w * 16 + (lane >> 2);
  int scp = lane & 3;
  int sy = y0 + (sr >> 4), sx = x0 + (sr & 15);
  uint16_t* lds0 = &As[0][0] + sr * 32 + scp * 8;  // == wave base + lane*16B (linear)

  float bv[4];
#pragma unroll
  for (int n = 0; n < 4; ++n) bv[n] = bias[wc * 64 + n * 16 + lr];

  f32x4 acc[4][4];
#pragma unroll
  for (int m = 0; m < 4; ++m)
#pragma unroll
    for (int n = 0; n < 4; ++n) acc[m][n] = (f32x4){0.f, 0.f, 0.f, 0.f};

#define STAGE1(kt, buf)                                                                   \
  {                                                                                       \
    int t_ = (kt) / CBS, cb_ = (kt) - t_ * CBS;                                           \
    int dy_ = t_ / 3, dx_ = t_ - dy_ * 3;                                                 \
    const uint16_t* g_ =                                                                  \
        fcat + ((size_t)(b * HP + sy + dy_) * WP + (sx + dx_)) * CATC + cb_ * 32 + scp * 8; \
    gload16(g_, lds0 + (buf)*4096);                                                       \
  }

#define LOADB1(dst, kt)                                                       \
  {                                                                           \
    const uint16_t* s_ = wp + ((size_t)(kt)*256 + wc * 64 + lr) * 32 + lk * 8; \
    _Pragma("unroll") for (int n_ = 0; n_ < 4; ++n_) dst[n_] =                \
        *(const bf16x8*)(s_ + (size_t)n_ * 16 * 32);                          \
  }

  bf16x8 bcur[4], bnext[4];
  STAGE1(0, 0);
  STAGE1(1, 1);
  LOADB1(bcur, 0);
  asm volatile("s_waitcnt vmcnt(5)" ::: "memory");  // stage0 done; stage1+B0 in flight
  __builtin_amdgcn_s_barrier();

  for (int kt = 0; kt < NT; ++kt) {
    int nkt = kt + 2 < NT ? kt + 2 : NT - 1;  // clamped tail -> unread buffer, uniform count
    STAGE1(nkt, (kt + 2) % 3);
    int bkt = kt + 1 < NT ? kt + 1 : NT - 1;
    LOADB1(bnext, bkt);
    const uint16_t* a = &As[kt % 3][0];
    bf16x8 af[4];
#pragma unroll
    for (int m = 0; m < 4; ++m)
      af[m] = *(const bf16x8*)(a + (wr * 64 + m * 16 + lr) * 32 + lk * 8);
#pragma unroll
    for (int m = 0; m < 4; ++m)
#pragma unroll
      for (int n = 0; n < 4; ++n)
        acc[m][n] = __builtin_amdgcn_mfma_f32_16x16x32_bf16(af[m], bcur[n], acc[m][n], 0, 0, 0);
#pragma unroll
    for (int n = 0; n < 4; ++n) bcur[n] = bnext[n];
    // stage kt+1 (issued last iter, older than B(kt+1)) must be done before next read:
    asm volatile("s_waitcnt vmcnt(5)" ::: "memory");  // allow stage(kt+2) + B(kt+1) in flight
    __builtin_amdgcn_s_barrier();
  }

  // epilogue: D col = co (lane&15), row = px ((lane>>4)*4+j); relu -> hbuf NHWC-pad bf16
#pragma unroll
  for (int m = 0; m < 4; ++m) {
#pragma unroll
    for (int j = 0; j < 4; ++j) {
      int px = wr * 64 + m * 16 + lk * 4 + j;
      int py = px >> 4, pxx = px & 15;
      size_t base = ((size_t)(b * HP + y0 + py + 1) * WP + (x0 + pxx + 1)) * NC;
#pragma unroll
      for (int n = 0; n < 4; ++n) {
        float v = acc[m][n][j] + bv[n];
        v = v > 0.f ? v : 0.f;
        hbuf[base + wc * 64 + n * 16 + lr] = f2bf(v);
      }
    }
  }
#undef STAGE1
#undef LOADB1
}

// ---------------- conv2: same pipeline, operands swapped ----------------
// A = weights [256 co][32] in LDS (triple-buffered, gload_lds); B = activations (hbuf)
// global->reg 1-step prefetch. D: row = co, col = px -> coalesced f32 NCHW epilogue.
__global__ __launch_bounds__(512, 2) void conv2_kernel(const uint16_t* __restrict__ hbuf,
                                                       const uint16_t* __restrict__ wp,
                                                       const float* __restrict__ bias,
                                                       const float* __restrict__ f1,
                                                       float* __restrict__ out) {
  constexpr int CBS = 8, NT = 72;
  __shared__ __align__(16) uint16_t Ws[3][256 * 32];  // 3 x 16 KB
  int tid = threadIdx.x;
  int w = tid >> 6, lane = tid & 63;
  int lr = lane & 15, lk = lane >> 4;
  int wq = w & 3;    // co quarter (M)
  int wph = w >> 2;  // px half (N)

  int orig = blockIdx.x;
  int swz = (orig & 7) * 30 + (orig >> 3);
  int b = swz / 120, rem = swz % 120;
  int xt = rem / 12, yt = rem % 12;
  int x0 = xt * 16, y0 = yt * 8;

  int scp = lane & 3;

  float bv[4][4];
#pragma unroll
  for (int m = 0; m < 4; ++m)
#pragma unroll
    for (int j = 0; j < 4; ++j) bv[m][j] = bias[wq * 64 + m * 16 + lk * 4 + j];

  f32x4 acc[4][4];
#pragma unroll
  for (int m = 0; m < 4; ++m)
#pragma unroll
    for (int n = 0; n < 4; ++n) acc[m][n] = (f32x4){0.f, 0.f, 0.f, 0.f};

#define STAGE2(kt, buf)                                                        \
  {                                                                            \
    const uint16_t* g_ = wp + ((size_t)(kt)*256) * 32;                         \
    _Pragma("unroll") for (int j_ = 0; j_ < 2; ++j_) {                         \
      int r_ = w * 32 + j_ * 16 + (lane >> 2);                                 \
      gload16(g_ + r_ * 32 + scp * 8, &Ws[buf][0] + r_ * 32 + scp * 8);        \
    }                                                                          \
  }

#define LOADX2(dst, kt)                                                                     \
  {                                                                                         \
    int t_ = (kt) >> 3, cb_ = (kt)&7;                                                       \
    int dy_ = t_ / 3, dx_ = t_ - dy_ * 3;                                                   \
    _Pragma("unroll") for (int n_ = 0; n_ < 4; ++n_) {                                      \
      const uint16_t* g_ = hbuf +                                                           \
          ((size_t)(b * HP + y0 + wph * 4 + n_ + dy_) * WP + (x0 + lr + dx_)) * NC +        \
          cb_ * 32 + lk * 8;                                                                \
      dst[n_] = *(const bf16x8*)g_;                                                         \
    }                                                                                       \
  }

  bf16x8 xcur[4], xnext[4];
  STAGE2(0, 0);
  STAGE2(1, 1);
  LOADX2(xcur, 0);
  asm volatile("s_waitcnt vmcnt(6)" ::: "memory");  // stage0 (2) done; stage1 (2) + X0 (4) in flight
  __builtin_amdgcn_s_barrier();

  for (int kt = 0; kt < NT; ++kt) {
    int nkt = kt + 2 < NT ? kt + 2 : NT - 1;
    STAGE2(nkt, (kt + 2) % 3);
    int bkt = kt + 1 < NT ? kt + 1 : NT - 1;
    LOADX2(xnext, bkt);
    const uint16_t* a = &Ws[kt % 3][0];
    bf16x8 af[4];
#pragma unroll
    for (int m = 0; m < 4; ++m)
      af[m] = *(const bf16x8*)(a + (wq * 64 + m * 16 + lr) * 32 + lk * 8);
#pragma unroll
    for (int m = 0; m < 4; ++m)
#pragma unroll
      for (int n = 0; n < 4; ++n)
        acc[m][n] = __builtin_amdgcn_mfma_f32_16x16x32_bf16(af[m], xcur[n], acc[m][n], 0, 0, 0);
#pragma unroll
    for (int n = 0; n < 4; ++n) xcur[n] = xnext[n];
    asm volatile("s_waitcnt vmcnt(6)" ::: "memory");
    __builtin_amdgcn_s_barrier();
  }

  // epilogue: row = co = wq*64+m*16+lk*4+j, col = px -> (py = wph*4+n, pxx = lr); f32 NCHW
#pragma unroll
  for (int m = 0; m < 4; ++m) {
#pragma unroll
    for (int j = 0; j < 4; ++j) {
      int co = wq * 64 + m * 16 + lk * 4 + j;
#pragma unroll
      for (int n = 0; n < 4; ++n) {
        int y = y0 + wph * 4 + n;
        size_t idx = ((size_t)(b * NC + co) * NH + y) * NW + x0 + lr;
        out[idx] = acc[m][n][j] + bv[m][j] + f1[idx];
      }
    }
  }
#undef STAGE2
#undef LOADX2
}

extern "C" void kernel_launch(void* const* d_in, const int* in_sizes, int n_in,
                              void* d_out, int out_size, void* d_ws, size_t ws_size,
                              hipStream_t stream) {
  (void)in_sizes; (void)n_in; (void)out_size; (void)ws_size;
  const float* f0 = (const float*)d_in[0];
  const float* f1 = (const float*)d_in[1];
  const float* W1 = (const float*)d_in[2];
  const float* b1 = (const float*)d_in[3];
  const float* W2 = (const float*)d_in[4];
  const float* b2 = (const float*)d_in[5];
  float* out = (float*)d_out;

  char* ws = (char*)d_ws;
  size_t s_fcat = (size_t)NB * HP * WP * CATC * 2;  // 48.8 MB
  size_t s_f1p8 = (size_t)NB * P8H * P8W * NC * 2;  // 20.2 MB
  size_t s_h = (size_t)NB * HP * WP * NC * 2;       // 16.3 MB
  size_t s_bp1 = (size_t)9 * 24 * 256 * 32 * 2;     // 3.5 MB
  uint16_t* fcat = (uint16_t*)ws;
  uint16_t* f1p8 = (uint16_t*)(ws + s_fcat);
  uint16_t* hbuf = (uint16_t*)(ws + s_fcat + s_f1p8);
  uint16_t* bp1 = (uint16_t*)(ws + s_fcat + s_f1p8 + s_h);
  uint16_t* bp2 = (uint16_t*)(ws + s_fcat + s_f1p8 + s_h + s_bp1);

  hipMemsetAsync(fcat, 0, s_fcat, stream);
  hipMemsetAsync(f1p8, 0, s_f1p8, stream);
  hipMemsetAsync(hbuf, 0, s_h, stream);

  wprep_kernel<<<256, 256, 0, stream>>>(W1, bp1, 768);
  wprep_kernel<<<256, 256, 0, stream>>>(W2, bp2, 256);
  transpose_kernel<<<dim3(5, 96, 32), 256, 0, stream>>>(f0, f1, fcat, f1p8);
  corr_kernel<<<dim3(960, 2), 256, 0, stream>>>(fcat, f1p8, fcat);
  conv1_kernel<<<240, 512, 0, stream>>>(fcat, bp1, b1, hbuf);
  conv2_kernel<<<240, 512, 0, stream>>>(hbuf, bp2, b2, f1, out);
}